// Round 9
// baseline (58.801 us; speedup 1.0000x reference)
//
#include <hip/hip_runtime.h>

#define BATCH 32
#define SEQ   2048
#define KD    512
#define QD    1024
#define HD    128

#define NT 16          // K-steps of 32
#define ROWS 64        // rows per block (16 per wave)
#define NCHUNK 32      // 64-row chunks per batch

typedef float    f32x4 __attribute__((ext_vector_type(4)));
typedef _Float16 f16x8 __attribute__((ext_vector_type(8)));
typedef unsigned int u32;

__device__ __forceinline__ u32 pack2h(float a, float b) {
    _Float16 ha = (_Float16)a, hb = (_Float16)b;   // v_cvt_f16_f32 (RNE)
    unsigned short ua = __builtin_bit_cast(unsigned short, ha);
    unsigned short ub = __builtin_bit_cast(unsigned short, hb);
    return (u32)ua | ((u32)ub << 16);
}

// 16 fp32 (f32x4[4]) -> two uint4 of packed f16
__device__ __forceinline__ void cvt16(const f32x4 a[4], uint4& h0, uint4& h1) {
    h0 = make_uint4(pack2h(a[0][0], a[0][1]), pack2h(a[0][2], a[0][3]),
                    pack2h(a[1][0], a[1][1]), pack2h(a[1][2], a[1][3]));
    h1 = make_uint4(pack2h(a[2][0], a[2][1]), pack2h(a[2][2], a[2][3]),
                    pack2h(a[3][0], a[3][1]), pack2h(a[3][2], a[3][3]));
}

// two f32x4 (8 floats) -> f16x8
__device__ __forceinline__ f16x8 cvtA4(const f32x4& r0, const f32x4& r1) {
    uint4 u = make_uint4(pack2h(r0[0], r0[1]), pack2h(r0[2], r0[3]),
                         pack2h(r1[0], r1[1]), pack2h(r1[2], r1[3]));
    return __builtin_bit_cast(f16x8, u);
}

__device__ __forceinline__ void gload_lds16(const void* g, void* l) {
    __builtin_amdgcn_global_load_lds(
        (const __attribute__((address_space(1))) unsigned int*)g,
        (__attribute__((address_space(3))) unsigned int*)l, 16, 0, 0);
}

// ---------------------------------------------------------------- prep
// blocks [0,512): q_proj ; blocks [512,528): W2 -> f16 swizzled 8 KB images
__global__ __launch_bounds__(256) void prep_kernel(
        const float* __restrict__ query, const float* __restrict__ W1,
        const float* __restrict__ W2, float* __restrict__ qp,
        char* __restrict__ w2img) {
    int blk = blockIdx.x;
    int tid = threadIdx.x;
    if (blk < 512) {
        int b = blk >> 4, hg = blk & 15;
        int wave = tid >> 6, lane = tid & 63;
        int h = hg * 8 + wave * 2 + (lane >> 5);
        int l32 = lane & 31;
        const float* q = query + (size_t)b * QD;
        const float* w = W1 + (size_t)h * QD;
        float acc = 0.f;
        #pragma unroll
        for (int i = 0; i < 8; ++i) {
            float4 qv = *(const float4*)(q + i * 128 + l32 * 4);
            float4 wv = *(const float4*)(w + i * 128 + l32 * 4);
            acc += qv.x * wv.x + qv.y * wv.y + qv.z * wv.z + qv.w * wv.w;
        }
        #pragma unroll
        for (int off = 16; off >= 1; off >>= 1) acc += __shfl_xor(acc, off);
        if (l32 == 0) qp[b * HD + h] = acc;
    } else {
        int c = blk - 512;              // 32-col chunk 0..15
        int row = tid >> 1;             // h row 0..127
        int scol = (tid & 1) * 16;      // element col within 32
        const float* src = W2 + (size_t)row * KD + c * 32 + scol;
        f32x4 a[4];
        #pragma unroll
        for (int i = 0; i < 4; ++i) a[i] = *(const f32x4*)(src + i * 4);
        uint4 h0, h1;
        cvt16(a, h0, h1);
        int sw = (row & 7) << 4;
        int b0 = c * 8192 + ((row * 64 + scol * 2) ^ sw);
        int b1 = c * 8192 + ((row * 64 + scol * 2 + 16) ^ sw);
        *(uint4*)(w2img + b0) = h0;
        *(uint4*)(w2img + b1) = h1;
    }
}

// ---------------------------------------------------------------- score + ctx partial
// 4 waves x 16 rows = 64 rows/block, 1024 blocks, 3 blocks/CU (12 waves/CU).
// Counted-vmcnt pipeline: 3 LDS slots (A fp32 8 KB + B f16 8 KB each),
// stage-ahead-1 via global_load_lds ONLY, asm s_waitcnt vmcnt(4) + asm
// s_barrier (both "memory"-fenced). 1024 blocks on 768 block-slots ->
// staggered generations: late blocks' HBM stream overlaps early blocks'
// epilogue + ctx-GEMV tails.
__global__ __launch_bounds__(256, 3) void score_ctx_kernel(
        const float* __restrict__ keys, const char* __restrict__ w2img,
        const float* __restrict__ qp, const float* __restrict__ V,
        float* __restrict__ score_out, float* __restrict__ part_m,
        float* __restrict__ part_l, float* __restrict__ part_c) {
    __shared__ __align__(16) char slab[3][16384];   // [slot][A 8K | B 8K]
    __shared__ float sc[ROWS];
    __shared__ float pb[ROWS];

    const int blk  = blockIdx.x;          // 0..1023
    const int m0   = blk * ROWS;
    const int b    = blk >> 5;            // 32 chunks per batch
    const int tid  = threadIdx.x;
    const int wave = tid >> 6;
    const int lane = tid & 63;
    const int l15  = lane & 15;
    const int l4   = lane >> 4;

    // epilogue operands BEFORE the pipeline (safe: complete early; vmcnt
    // retires in order so in-flight prologue loads still drain correctly)
    float qv[8], vv[8];
    #pragma unroll
    for (int hj = 0; hj < 8; ++hj) {
        qv[hj] = qp[b * HD + hj * 16 + l15];
        vv[hj] = V[hj * 16 + l15];
    }

    // A staging source (per-lane, inverse-swizzled granule):
    // instr i of tile t: row = m0 + wave*16 + i*8 + (lane>>3),
    // granule byte = ((lane&7)*16) ^ ((lane>>3)<<4), + t*128
    const char* asrc0 = (const char*)keys
        + (size_t)(m0 + wave * 16 + (lane >> 3)) * (KD * 4)
        + (((lane & 7) * 16) ^ ((lane >> 3) << 4));

    // A read offsets: R = wave*16 + l15, byte R*128 + (l4*32 ^ swz)
    const int swz = (l15 & 7) << 4;
    const int ar0 = (wave * 16 + l15) * 128;
    const int ac0 = (l4 * 32) ^ swz;
    const int ac1 = (l4 * 32 + 16) ^ swz;
    // B frag byte offset within the slot's 8 KB image region
    const int boff0 = 8192 + ((l15 * 64 + l4 * 16) ^ swz);

    f32x4 acc[8];
    #pragma unroll
    for (int hj = 0; hj < 8; ++hj) acc[hj] = (f32x4)0.f;

#define STAGE(slot, t) { \
        char* as_ = slab[slot]; \
        gload_lds16(asrc0 + 0 * 16384 + (t) * 128, as_ + wave * 2048 + 0 * 1024); \
        gload_lds16(asrc0 + 1 * 16384 + (t) * 128, as_ + wave * 2048 + 1 * 1024); \
        const char* g_ = w2img + (t) * 8192 + wave * 2048 + lane * 16; \
        gload_lds16(g_,        as_ + 8192 + wave * 2048); \
        gload_lds16(g_ + 1024, as_ + 8192 + wave * 2048 + 1024); }

    // prologue: stage tile 0 into slot 0
    STAGE(0, 0)

    #pragma unroll
    for (int t = 0; t < NT; ++t) {
        const int cs = t % 3;
        if (t + 1 < NT) STAGE((t + 1) % 3, t + 1)

        // drain tile t's 4 loads; leave tile t+1's 4 in flight
        if (t + 1 < NT) asm volatile("s_waitcnt vmcnt(4)" ::: "memory");
        else            asm volatile("s_waitcnt vmcnt(0)" ::: "memory");
        asm volatile("s_barrier" ::: "memory");

        const char* as = slab[cs];
        f32x4 lo = *(const f32x4*)(as + ar0 + ac0);
        f32x4 hi = *(const f32x4*)(as + ar0 + ac1);
        f16x8 af = cvtA4(lo, hi);
        __builtin_amdgcn_s_setprio(1);
        #pragma unroll
        for (int hj = 0; hj < 8; ++hj) {
            f16x8 bh = *(const f16x8*)(as + boff0 + hj * 1024);
            acc[hj] = __builtin_amdgcn_mfma_f32_16x16x32_f16(af, bh, acc[hj], 0, 0, 0);
        }
        __builtin_amdgcn_s_setprio(0);
    }
#undef STAGE

    // scores; C/D: col(h)=l15, row(m)=l4*4+j
    #pragma unroll
    for (int j = 0; j < 4; ++j) {
        float p = 0.f;
        #pragma unroll
        for (int hj = 0; hj < 8; ++hj) {
            float x = qv[hj] + acc[hj][j];
            float e = __expf(2.f * x);
            float th = 1.f - 2.f * __builtin_amdgcn_rcpf(1.f + e);
            p += th * vv[hj];
        }
        #pragma unroll
        for (int off = 1; off < 16; off <<= 1) p += __shfl_xor(p, off);
        if (l15 == 0) {
            int r = wave * 16 + l4 * 4 + j;
            score_out[m0 + r] = p;
            sc[r] = p;
        }
    }
    __syncthreads();

    // block softmax partials over 64 rows (all waves compute identically)
    float s_val = sc[lane];
    float mx = s_val;
    #pragma unroll
    for (int off = 32; off >= 1; off >>= 1) mx = fmaxf(mx, __shfl_xor(mx, off));
    float p = __expf(s_val - mx);
    float ls = p;
    #pragma unroll
    for (int off = 32; off >= 1; off >>= 1) ls += __shfl_xor(ls, off);
    if (wave == 0) pb[lane] = p;
    if (tid == 0) {
        part_m[blk] = mx;
        part_l[blk] = ls;
    }
    __syncthreads();

    // context partial GEMV: c[col] = sum_s pb[s] * keys[m0+s, col]  (L2/L3)
    int col = tid * 2;
    float c0 = 0.f, c1 = 0.f;
    const float* kb2 = keys + (size_t)m0 * KD + col;
    #pragma unroll 8
    for (int s = 0; s < ROWS; ++s) {
        float w = pb[s];
        float2 kv = *(const float2*)(kb2 + (size_t)s * KD);
        c0 = fmaf(w, kv.x, c0);
        c1 = fmaf(w, kv.y, c1);
    }
    *(float2*)(part_c + (size_t)blk * KD + col) = make_float2(c0, c1);
}

// ---------------------------------------------------------------- finalize
__global__ __launch_bounds__(256) void finalize_kernel(
        const float* __restrict__ part_m, const float* __restrict__ part_l,
        const float* __restrict__ part_c, float* __restrict__ ctx,
        float* __restrict__ wts) {
    __shared__ float eS[NCHUNK];
    int b = blockIdx.x;
    int tid = threadIdx.x;
    float M = -1e30f;
    #pragma unroll 8
    for (int i = 0; i < NCHUNK; ++i) M = fmaxf(M, part_m[b * NCHUNK + i]);
    if (tid < NCHUNK) eS[tid] = __expf(part_m[b * NCHUNK + tid] - M);
    __syncthreads();
    float L = 0.f;
    #pragma unroll 8
    for (int i = 0; i < NCHUNK; ++i) L += eS[i] * part_l[b * NCHUNK + i];
    float invL = 1.f / L;
    #pragma unroll
    for (int r = 0; r < 8; ++r) {
        int s = tid + r * 256;
        float scv = wts[b * SEQ + s];
        wts[b * SEQ + s] = __expf(scv - M) * invL;
    }
    int col = tid * 2;
    float c0 = 0.f, c1 = 0.f;
    #pragma unroll 8
    for (int i = 0; i < NCHUNK; ++i) {
        float w = eS[i];
        float2 pc = *(const float2*)(part_c + (size_t)(b * NCHUNK + i) * KD + col);
        c0 = fmaf(w, pc.x, c0);
        c1 = fmaf(w, pc.y, c1);
    }
    ctx[b * KD + col]     = c0 * invL;
    ctx[b * KD + col + 1] = c1 * invL;
}

// ---------------------------------------------------------------- launch
extern "C" void kernel_launch(void* const* d_in, const int* in_sizes, int n_in,
                              void* d_out, int out_size, void* d_ws, size_t ws_size,
                              hipStream_t stream) {
    const float* query = (const float*)d_in[0];
    const float* keys  = (const float*)d_in[1];
    const float* W1    = (const float*)d_in[2];
    const float* W2    = (const float*)d_in[3];
    const float* V     = (const float*)d_in[4];

    float* ctx = (float*)d_out;
    float* wts = (float*)d_out + BATCH * KD;

    char* wsb     = (char*)d_ws;
    float* qp     = (float*)wsb;                       // 16 KB
    char*  w2img  = wsb + 16 * 1024;                   // 128 KB
    float* part_m = (float*)(wsb + 144 * 1024);        // 4 KB
    float* part_l = (float*)(wsb + 148 * 1024);        // 4 KB
    float* part_c = (float*)(wsb + 152 * 1024);        // 2 MB

    prep_kernel<<<528, 256, 0, stream>>>(query, W1, W2, qp, w2img);
    score_ctx_kernel<<<BATCH * NCHUNK, 256, 0, stream>>>(
        keys, w2img, qp, V, wts, part_m, part_l, part_c);
    finalize_kernel<<<BATCH, 256, 0, stream>>>(part_m, part_l, part_c, ctx, wts);
}

// Round 10
// 54.113 us; speedup vs baseline: 1.0866x; 1.0866x over previous
//
#include <hip/hip_runtime.h>

#define BATCH 32
#define SEQ   2048
#define KD    512
#define QD    1024
#define HD    128

#define NT 16          // K-steps of 32
#define ROWS 32        // rows per block
#define NCHUNK 64      // 32-row chunks per batch

typedef float    f32x4 __attribute__((ext_vector_type(4)));
typedef _Float16 f16x8 __attribute__((ext_vector_type(8)));
typedef unsigned int u32;

__device__ __forceinline__ u32 pack2h(float a, float b) {
    _Float16 ha = (_Float16)a, hb = (_Float16)b;   // v_cvt_f16_f32 (RNE)
    unsigned short ua = __builtin_bit_cast(unsigned short, ha);
    unsigned short ub = __builtin_bit_cast(unsigned short, hb);
    return (u32)ua | ((u32)ub << 16);
}

// ---------------------------------------------------------------- prep
// blocks [0,512): q_proj
// blocks [512,528): W2 -> per-fragment f16 images (R4-verified layout):
//   w2img[(t*512 + hj*64 + lane)*16] = f16 W2[hj*16+(lane&15)][t*32+(lane>>4)*8 ..+8)
__global__ __launch_bounds__(256) void prep_kernel(
        const float* __restrict__ query, const float* __restrict__ W1,
        const float* __restrict__ W2, float* __restrict__ qp,
        char* __restrict__ w2img) {
    int blk = blockIdx.x;
    int tid = threadIdx.x;
    if (blk < 512) {
        int b = blk >> 4, hg = blk & 15;
        int wave = tid >> 6, lane = tid & 63;
        int h = hg * 8 + wave * 2 + (lane >> 5);
        int l32 = lane & 31;
        const float* q = query + (size_t)b * QD;
        const float* w = W1 + (size_t)h * QD;
        float acc = 0.f;
        #pragma unroll
        for (int i = 0; i < 8; ++i) {
            float4 qv = *(const float4*)(q + i * 128 + l32 * 4);
            float4 wv = *(const float4*)(w + i * 128 + l32 * 4);
            acc += qv.x * wv.x + qv.y * wv.y + qv.z * wv.z + qv.w * wv.w;
        }
        #pragma unroll
        for (int off = 16; off >= 1; off >>= 1) acc += __shfl_xor(acc, off);
        if (l32 == 0) qp[b * HD + h] = acc;
    } else {
        int t = blk - 512;
        #pragma unroll
        for (int rep = 0; rep < 2; ++rep) {
            int f  = tid + rep * 256;        // frag 0..511
            int hj = f >> 6;
            int ln = f & 63;
            int r  = hj * 16 + (ln & 15);
            int c  = t * 32 + (ln >> 4) * 8;
            const float* src = W2 + (size_t)r * KD + c;
            float4 v0 = *(const float4*)(src);
            float4 v1 = *(const float4*)(src + 4);
            uint4 u = make_uint4(pack2h(v0.x, v0.y), pack2h(v0.z, v0.w),
                                 pack2h(v1.x, v1.y), pack2h(v1.z, v1.w));
            *(uint4*)(w2img + ((size_t)t * 512 + f) * 16) = u;
        }
    }
}

// ---------------------------------------------------------------- score + ctx (single pass)
// 32 rows/block, 2048 blocks, 4 blocks/CU (16 waves/CU).
// Phase 1: stage keys tile ONCE -> swizzled f16 LDS (serves MFMA A *and* ctx GEMV).
// Phase 2: K-loop, NO barriers: wave w owns hj = 2w,2w+1; A from LDS,
//          B direct from per-frag w2img (L2). 4 MFMAs/step.
// Phase 3: cross-wave score reduce + tanh/V epilogue + softmax partials.
// Phase 4: ctx partial GEMV entirely from LDS f16 tile.
__global__ __launch_bounds__(256, 4) void score_ctx_kernel(
        const float* __restrict__ keys, const char* __restrict__ w2img,
        const float* __restrict__ qp, const float* __restrict__ V,
        float* __restrict__ score_out, float* __restrict__ part_m,
        float* __restrict__ part_l, float* __restrict__ part_c) {
    __shared__ __align__(16) char kf16[ROWS * 1024];   // 32 KB swizzled f16 keys
    __shared__ float wpart[4][ROWS];
    __shared__ float pb[ROWS];

    const int blk  = blockIdx.x;          // 0..2047
    const int m0   = blk * ROWS;
    const int b    = blk >> 6;            // 64 chunks per batch
    const int tid  = threadIdx.x;
    const int wave = tid >> 6;
    const int lane = tid & 63;
    const int l15  = lane & 15;
    const int l4   = lane >> 4;

    // ---- phase 1: keys tile -> f16 swizzled LDS (read keys exactly once)
    const float4* src = (const float4*)(keys + (size_t)m0 * KD);
    #pragma unroll
    for (int i = 0; i < 16; ++i) {
        int f = i * 256 + tid;            // 16B fp32 chunk index, 0..4095
        float4 v = src[f];
        int row = f >> 7;                 // 128 chunks per 2 KB row
        int dst = (row * 1024 + (f & 127) * 8) ^ ((row & 7) << 4);
        *(uint2*)(kf16 + dst) = make_uint2(pack2h(v.x, v.y), pack2h(v.z, v.w));
    }
    __syncthreads();

    // ---- phase 2: K-loop, barrier-free
    const int hj0 = wave * 2;
    const char* bsrc = w2img + ((size_t)hj0 * 64 + lane) * 16;  // +t*8192, +1024 for hj1
    const int aswz = (l15 & 7) << 4;
    const int arow0 = l15 * 1024;         // rows 0..15  (mi=0)
    const int arow1 = (16 + l15) * 1024;  // rows 16..31 (mi=1)

    f32x4 acc[2][2];                      // [mi][hj-local]
    #pragma unroll
    for (int mi = 0; mi < 2; ++mi)
        #pragma unroll
        for (int hl = 0; hl < 2; ++hl)
            acc[mi][hl] = (f32x4)0.f;

    #pragma unroll
    for (int t = 0; t < NT; ++t) {
        int ac = (l4 * 16 + t * 64) ^ aswz;
        f16x8 a0 = *(const f16x8*)(kf16 + arow0 + ac);
        f16x8 a1 = *(const f16x8*)(kf16 + arow1 + ac);
        f16x8 b0 = *(const f16x8*)(bsrc + (size_t)t * 8192);
        f16x8 b1 = *(const f16x8*)(bsrc + (size_t)t * 8192 + 1024);
        acc[0][0] = __builtin_amdgcn_mfma_f32_16x16x32_f16(a0, b0, acc[0][0], 0, 0, 0);
        acc[0][1] = __builtin_amdgcn_mfma_f32_16x16x32_f16(a0, b1, acc[0][1], 0, 0, 0);
        acc[1][0] = __builtin_amdgcn_mfma_f32_16x16x32_f16(a1, b0, acc[1][0], 0, 0, 0);
        acc[1][1] = __builtin_amdgcn_mfma_f32_16x16x32_f16(a1, b1, acc[1][1], 0, 0, 0);
    }

    // ---- phase 3: per-wave partial scores (this wave's 32 h-values)
    float qv0 = qp[b * HD + hj0 * 16 + l15];
    float qv1 = qp[b * HD + hj0 * 16 + 16 + l15];
    float vv0 = V[hj0 * 16 + l15];
    float vv1 = V[hj0 * 16 + 16 + l15];
    #pragma unroll
    for (int mi = 0; mi < 2; ++mi) {
        #pragma unroll
        for (int j = 0; j < 4; ++j) {
            float x0 = qv0 + acc[mi][0][j];
            float x1 = qv1 + acc[mi][1][j];
            float e0 = __expf(2.f * x0);
            float e1 = __expf(2.f * x1);
            float p = (1.f - 2.f * __builtin_amdgcn_rcpf(1.f + e0)) * vv0
                    + (1.f - 2.f * __builtin_amdgcn_rcpf(1.f + e1)) * vv1;
            #pragma unroll
            for (int off = 1; off < 16; off <<= 1) p += __shfl_xor(p, off);
            if (l15 == 0) wpart[wave][mi * 16 + l4 * 4 + j] = p;
        }
    }
    __syncthreads();

    // full score per row + block softmax partials (all waves compute; wave 0 writes)
    int r = lane & 31;
    float prow = wpart[0][r] + wpart[1][r] + wpart[2][r] + wpart[3][r];
    float mx = prow;
    #pragma unroll
    for (int off = 1; off < 32; off <<= 1) mx = fmaxf(mx, __shfl_xor(mx, off));
    float e = __expf(prow - mx);
    float ls = e;
    #pragma unroll
    for (int off = 1; off < 32; off <<= 1) ls += __shfl_xor(ls, off);
    if (wave == 0) {
        if (lane < 32) {
            score_out[m0 + r] = prow;
            pb[r] = e;
        }
        if (lane == 0) {
            part_m[blk] = mx;
            part_l[blk] = ls;
        }
    }
    __syncthreads();

    // ---- phase 4: ctx partial GEMV from the LDS f16 tile (no global re-read)
    int col = tid * 2;                    // cols 0..510
    float c0 = 0.f, c1 = 0.f;
    #pragma unroll 8
    for (int s = 0; s < ROWS; ++s) {
        float w = pb[s];
        u32 kk = *(const u32*)(kf16 + ((s * 1024 + col * 2) ^ ((s & 7) << 4)));
        float k0 = (float)__builtin_bit_cast(_Float16, (unsigned short)(kk & 0xffff));
        float k1 = (float)__builtin_bit_cast(_Float16, (unsigned short)(kk >> 16));
        c0 = fmaf(w, k0, c0);
        c1 = fmaf(w, k1, c1);
    }
    *(float2*)(part_c + (size_t)blk * KD + col) = make_float2(c0, c1);
}

// ---------------------------------------------------------------- finalize
__global__ __launch_bounds__(256) void finalize_kernel(
        const float* __restrict__ part_m, const float* __restrict__ part_l,
        const float* __restrict__ part_c, float* __restrict__ ctx,
        float* __restrict__ wts) {
    __shared__ float eS[NCHUNK];
    int b = blockIdx.x;
    int tid = threadIdx.x;
    float M = -1e30f;
    #pragma unroll 8
    for (int i = 0; i < NCHUNK; ++i) M = fmaxf(M, part_m[b * NCHUNK + i]);
    if (tid < NCHUNK) eS[tid] = __expf(part_m[b * NCHUNK + tid] - M);
    __syncthreads();
    float L = 0.f;
    #pragma unroll 8
    for (int i = 0; i < NCHUNK; ++i) L += eS[i] * part_l[b * NCHUNK + i];
    float invL = 1.f / L;
    #pragma unroll
    for (int r = 0; r < 8; ++r) {
        int s = tid + r * 256;
        float scv = wts[b * SEQ + s];
        wts[b * SEQ + s] = __expf(scv - M) * invL;
    }
    int col = tid * 2;
    float c0 = 0.f, c1 = 0.f;
    #pragma unroll 8
    for (int i = 0; i < NCHUNK; ++i) {
        float w = eS[i];
        float2 pc = *(const float2*)(part_c + (size_t)(b * NCHUNK + i) * KD + col);
        c0 = fmaf(w, pc.x, c0);
        c1 = fmaf(w, pc.y, c1);
    }
    ctx[b * KD + col]     = c0 * invL;
    ctx[b * KD + col + 1] = c1 * invL;
}

// ---------------------------------------------------------------- launch
extern "C" void kernel_launch(void* const* d_in, const int* in_sizes, int n_in,
                              void* d_out, int out_size, void* d_ws, size_t ws_size,
                              hipStream_t stream) {
    const float* query = (const float*)d_in[0];
    const float* keys  = (const float*)d_in[1];
    const float* W1    = (const float*)d_in[2];
    const float* W2    = (const float*)d_in[3];
    const float* V     = (const float*)d_in[4];

    float* ctx = (float*)d_out;
    float* wts = (float*)d_out + BATCH * KD;

    char* wsb     = (char*)d_ws;
    float* qp     = (float*)wsb;                       // 16 KB
    char*  w2img  = wsb + 16 * 1024;                   // 128 KB
    float* part_m = (float*)(wsb + 144 * 1024);        // 8 KB
    float* part_l = (float*)(wsb + 152 * 1024);        // 8 KB
    float* part_c = (float*)(wsb + 160 * 1024);        // 4 MB

    prep_kernel<<<528, 256, 0, stream>>>(query, W1, W2, qp, w2img);
    score_ctx_kernel<<<BATCH * NCHUNK, 256, 0, stream>>>(
        keys, w2img, qp, V, wts, part_m, part_l, part_c);
    finalize_kernel<<<BATCH, 256, 0, stream>>>(part_m, part_l, part_c, ctx, wts);
}